// Round 4
// baseline (250.380 us; speedup 1.0000x reference)
//
#include <hip/hip_runtime.h>
#include <stdint.h>

// ---------------------------------------------------------------------------
// PatchEmbed + HMQConv2d fake-quant, fp32 I/O.
//   s_x = max(max|x|,1e-8)/127 ; s_w = max(max|w|,1e-8)/127
//   out[b, gx*28+gy, d] = (sum_k round(clamp(x/s_x))*round(clamp(w/s_w))) * s_x*s_w + b[d]
// GEMM M=50176, N=768, K=192. Integer codes (|q|<=127) -> bf16 MFMA, exact.
//
// Round-4 structure: NO LDS, NO barriers in the GEMM. An MFMA A/B fragment is
// 8 consecutive k = 8 contiguous floats of x (one patch row) / of w — so each
// lane builds fragments straight from global (2x float4 + in-register quant).
// K=192 is too short to amortize a staged 2-barrier pipeline (only 3 rounds);
// direct fragment loads turn the kernel into what it really is: write-bound
// (154 MB out => ~25 us floor) with MFMA+quant hidden underneath.
// 3 launches total; ws usage < 8 KB.
// ---------------------------------------------------------------------------

typedef short bf16x8 __attribute__((ext_vector_type(8)));  // 8 bf16 codes
using f32x4 = __attribute__((ext_vector_type(4))) float;

static __device__ __forceinline__ uint16_t f2bfbits(float f) {
  uint32_t u = __float_as_uint(f);
  u += 0x7FFFu + ((u >> 16) & 1u);   // RTNE (exact for small ints)
  return (uint16_t)(u >> 16);
}
static __device__ __forceinline__ uint32_t q2(float a, float b, float inv_s) {
  float qa = rintf(fminf(fmaxf(a * inv_s, -127.0f), 127.0f));
  float qb = rintf(fminf(fmaxf(b * inv_s, -127.0f), 127.0f));
  return (uint32_t)f2bfbits(qa) | ((uint32_t)f2bfbits(qb) << 16);
}
// 8 consecutive floats -> bf16x8 integer-code fragment
static __device__ __forceinline__ bf16x8 quant_frag(const float4* p, float inv_s) {
  float4 a0 = p[0], a1 = p[1];
  uint4 q;
  q.x = q2(a0.x, a0.y, inv_s);
  q.y = q2(a0.z, a0.w, inv_s);
  q.z = q2(a1.x, a1.y, inv_s);
  q.w = q2(a1.z, a1.w, inv_s);
  return __builtin_bit_cast(bf16x8, q);
}

// ---- absmax: blocks [0,1024) cover x, [1024,1088) cover w -----------------
#define NBX 1024
#define NBW 64
__global__ void absmax_k(const float4* __restrict__ x, int nx4,
                         const float4* __restrict__ w, int nw4,
                         float* __restrict__ partials) {
  __shared__ float red[4];
  float m = 0.0f;
  if (blockIdx.x < NBX) {
    for (int i = blockIdx.x * 256 + threadIdx.x; i < nx4; i += NBX * 256) {
      float4 u = x[i];
      m = fmaxf(m, fabsf(u.x)); m = fmaxf(m, fabsf(u.y));
      m = fmaxf(m, fabsf(u.z)); m = fmaxf(m, fabsf(u.w));
    }
  } else {
    for (int i = (blockIdx.x - NBX) * 256 + threadIdx.x; i < nw4; i += NBW * 256) {
      float4 u = w[i];
      m = fmaxf(m, fabsf(u.x)); m = fmaxf(m, fabsf(u.y));
      m = fmaxf(m, fabsf(u.z)); m = fmaxf(m, fabsf(u.w));
    }
  }
#pragma unroll
  for (int off = 32; off > 0; off >>= 1) m = fmaxf(m, __shfl_down(m, off, 64));
  if ((threadIdx.x & 63) == 0) red[threadIdx.x >> 6] = m;
  __syncthreads();
  if (threadIdx.x == 0) {
    m = fmaxf(fmaxf(red[0], red[1]), fmaxf(red[2], red[3]));
    partials[blockIdx.x] = m;
  }
}

// ---- finalize: partials -> slots[0]=s_x, slots[1]=s_w ---------------------
__global__ void finalize_k(const float* __restrict__ partials,
                           float* __restrict__ slots) {
  __shared__ float red[16];
  int tid = threadIdx.x;                 // 1024 threads
  float m = partials[tid];
#pragma unroll
  for (int off = 32; off > 0; off >>= 1) m = fmaxf(m, __shfl_down(m, off, 64));
  if ((tid & 63) == 0) red[tid >> 6] = m;
  __syncthreads();
  if (tid == 0) {
#pragma unroll
    for (int i = 1; i < 16; ++i) m = fmaxf(m, red[i]);
    slots[0] = fmaxf(m, 1e-8f) * (1.0f / 127.0f);
  }
  if (tid >= 64 && tid < 128) {          // wave 1: reduce the 64 w-partials
    float mw = partials[NBX + (tid - 64)];
#pragma unroll
    for (int off = 32; off > 0; off >>= 1) mw = fmaxf(mw, __shfl_down(mw, off, 64));
    if (tid == 64) slots[1] = fmaxf(mw, 1e-8f) * (1.0f / 127.0f);
  }
}

// ---------------------------------------------------------------------------
// GEMM, fragments direct from global with fused quant.
// mfma_f32_16x16x32_bf16 verified layouts (m89/m120):
//   A frag: A[m = lane&15][k = (lane>>4)*8 + j]
//   B frag: W[n = lane&15][k = (lane>>4)*8 + j]
//   D:      row = (lane>>4)*4 + reg, col = lane&15
// ---------------------------------------------------------------------------
__global__ __launch_bounds__(256) void gemm_k(
    const float4* __restrict__ x4, const float4* __restrict__ w4,
    const float* __restrict__ bias, const float* __restrict__ slots,
    float* __restrict__ out) {
  const int tid  = threadIdx.x;
  const int lane = tid & 63;
  const int wid  = tid >> 6;
  const int wm   = wid >> 1;   // 0..1
  const int wn   = wid & 1;    // 0..1
  const int lm   = lane & 15;
  const int lq   = lane >> 4;  // 0..3
  const int m0   = blockIdx.y * 128;
  const int n0   = blockIdx.x * 128;

  const float sx = slots[0];
  const float sw = slots[1];
  const float inv_sx = 1.0f / sx;
  const float inv_sw = 1.0f / sw;

  // A base (float4 units) at k=0 for each tm's row m:
  //   m = b*784 + gx*28 + gy ; addr(k) floats = ((b*3+c)*224 + gx*8 + p)*224 + gy*8
  int abase[4];
#pragma unroll
  for (int tm = 0; tm < 4; ++tm) {
    int m  = m0 + wm * 64 + tm * 16 + lm;
    int b  = m / 784;
    int rr = m - b * 784;
    int gx = rr / 28;
    int gy = rr - gx * 28;
    abase[tm] = (b * 672 + gx * 8) * 56 + gy * 2;   // b*3*224=672 rows
  }
  int bbase[4];
#pragma unroll
  for (int tn = 0; tn < 4; ++tn)
    bbase[tn] = (n0 + wn * 64 + tn * 16 + lm) * 48; // 192 floats = 48 float4

  f32x4 acc[4][4] = {};

#pragma unroll
  for (int ks = 0; ks < 6; ++ks) {                  // k = ks*32 + lq*8 + j
    const int c = ks >> 1;
    const int p = (ks & 1) * 4 + lq;
    const int aoff = c * 12544 + p * 56;            // c*(224*224/4) + p*(224/4)
    const int boff = ks * 8 + lq * 2;
    bf16x8 af[4], bf[4];
#pragma unroll
    for (int tm = 0; tm < 4; ++tm)
      af[tm] = quant_frag(&x4[abase[tm] + aoff], inv_sx);
#pragma unroll
    for (int tn = 0; tn < 4; ++tn)
      bf[tn] = quant_frag(&w4[bbase[tn] + boff], inv_sw);
#pragma unroll
    for (int tm = 0; tm < 4; ++tm)
#pragma unroll
      for (int tn = 0; tn < 4; ++tn)
        acc[tm][tn] = __builtin_amdgcn_mfma_f32_16x16x32_bf16(
            af[tm], bf[tn], acc[tm][tn], 0, 0, 0);
  }

  const float scale = sx * sw;
#pragma unroll
  for (int tn = 0; tn < 4; ++tn) {
    int col = n0 + wn * 64 + tn * 16 + lm;
    float bv = bias[col];
#pragma unroll
    for (int tm = 0; tm < 4; ++tm) {
      int rbase = m0 + wm * 64 + tm * 16 + lq * 4;
#pragma unroll
      for (int r = 0; r < 4; ++r)
        out[(size_t)(rbase + r) * 768 + col] = acc[tm][tn][r] * scale + bv;
    }
  }
}

// ---------------------------------------------------------------------------

extern "C" void kernel_launch(void* const* d_in, const int* in_sizes, int n_in,
                              void* d_out, int out_size, void* d_ws, size_t ws_size,
                              hipStream_t stream) {
  const float4* x = (const float4*)d_in[0];      // 9,633,792 fp32
  const float4* w = (const float4*)d_in[1];      //   147,456 fp32
  const float* bias = (const float*)d_in[2];     //       768 fp32
  float* out = (float*)d_out;                    // 38,535,168 fp32

  char* ws = (char*)d_ws;
  float* slots    = (float*)ws;                  // [0]=s_x, [1]=s_w
  float* partials = (float*)(ws + 256);          // 1088 floats

  const int nx4 = 9633792 / 4;   // 2,408,448
  const int nw4 = 147456 / 4;    //    36,864

  absmax_k<<<NBX + NBW, 256, 0, stream>>>(x, nx4, w, nw4, partials);
  finalize_k<<<1, 1024, 0, stream>>>(partials, slots);
  gemm_k<<<dim3(6, 392), 256, 0, stream>>>(x, w, bias, slots, out);
}

// Round 5
// 236.959 us; speedup vs baseline: 1.0566x; 1.0566x over previous
//
#include <hip/hip_runtime.h>
#include <stdint.h>

// ---------------------------------------------------------------------------
// PatchEmbed + HMQConv2d fake-quant, fp32 I/O.
//   s_x = max(max|x|,1e-8)/127 ; s_w = max(max|w|,1e-8)/127
//   out[b, gx*28+gy, d] = (sum_k qx*qw) * s_x*s_w + bias[d]
// GEMM M=50176, N=768, K=192; integer codes (|q|<=127) in bf16 MFMA = exact.
//
// Round-5: quantization fully hoisted out of the GEMM (r4 post-mortem:
// VALUBusy 40% vs MfmaUtil 5.7% — fused quant was 8x the MFMA work and
// redundant 6x for x, 392x for w). Aq[50176][192] + Wq[768][192] bf16 codes
// precomputed in ws; gemm is pure load+MFMA. Grid (392,6): 392%8==0 makes
// all 6 column tiles of a row-tile land on one XCD -> Aq slice L2-resident.
// ---------------------------------------------------------------------------

typedef short bf16x8 __attribute__((ext_vector_type(8)));  // 8 bf16 codes
using f32x4 = __attribute__((ext_vector_type(4))) float;

static __device__ __forceinline__ uint16_t f2bfbits(float f) {
  uint32_t u = __float_as_uint(f);
  u += 0x7FFFu + ((u >> 16) & 1u);   // RTNE (exact for small ints)
  return (uint16_t)(u >> 16);
}
static __device__ __forceinline__ uint32_t q2(float a, float b, float inv_s) {
  float qa = rintf(fminf(fmaxf(a * inv_s, -127.0f), 127.0f));
  float qb = rintf(fminf(fmaxf(b * inv_s, -127.0f), 127.0f));
  return (uint32_t)f2bfbits(qa) | ((uint32_t)f2bfbits(qb) << 16);
}
static __device__ __forceinline__ uint4 quant8(float4 a0, float4 a1, float inv_s) {
  uint4 q;
  q.x = q2(a0.x, a0.y, inv_s);
  q.y = q2(a0.z, a0.w, inv_s);
  q.z = q2(a1.x, a1.y, inv_s);
  q.w = q2(a1.z, a1.w, inv_s);
  return q;
}

// ---- absmax: blocks [0,1024) cover x, [1024,1088) cover w -----------------
#define NBX 1024
#define NBW 64
__global__ void absmax_k(const float4* __restrict__ x, int nx4,
                         const float4* __restrict__ w, int nw4,
                         float* __restrict__ partials) {
  __shared__ float red[4];
  float m = 0.0f;
  if (blockIdx.x < NBX) {
    for (int i = blockIdx.x * 256 + threadIdx.x; i < nx4; i += NBX * 256) {
      float4 u = x[i];
      m = fmaxf(m, fabsf(u.x)); m = fmaxf(m, fabsf(u.y));
      m = fmaxf(m, fabsf(u.z)); m = fmaxf(m, fabsf(u.w));
    }
  } else {
    for (int i = (blockIdx.x - NBX) * 256 + threadIdx.x; i < nw4; i += NBW * 256) {
      float4 u = w[i];
      m = fmaxf(m, fabsf(u.x)); m = fmaxf(m, fabsf(u.y));
      m = fmaxf(m, fabsf(u.z)); m = fmaxf(m, fabsf(u.w));
    }
  }
#pragma unroll
  for (int off = 32; off > 0; off >>= 1) m = fmaxf(m, __shfl_down(m, off, 64));
  if ((threadIdx.x & 63) == 0) red[threadIdx.x >> 6] = m;
  __syncthreads();
  if (threadIdx.x == 0) {
    m = fmaxf(fmaxf(red[0], red[1]), fmaxf(red[2], red[3]));
    partials[blockIdx.x] = m;
  }
}

// ---- finalize: partials -> slots[0]=s_x, slots[1]=s_w ---------------------
__global__ void finalize_k(const float* __restrict__ partials,
                           float* __restrict__ slots) {
  __shared__ float red[16];
  int tid = threadIdx.x;                 // 1024 threads
  float m = partials[tid];
#pragma unroll
  for (int off = 32; off > 0; off >>= 1) m = fmaxf(m, __shfl_down(m, off, 64));
  if ((tid & 63) == 0) red[tid >> 6] = m;
  __syncthreads();
  if (tid == 0) {
#pragma unroll
    for (int i = 1; i < 16; ++i) m = fmaxf(m, red[i]);
    slots[0] = fmaxf(m, 1e-8f) * (1.0f / 127.0f);
  }
  if (tid >= 64 && tid < 128) {          // wave 1: reduce the 64 w-partials
    float mw = partials[NBX + (tid - 64)];
#pragma unroll
    for (int off = 32; off > 0; off >>= 1) mw = fmaxf(mw, __shfl_down(mw, off, 64));
    if (tid == 64) slots[1] = fmaxf(mw, 1e-8f) * (1.0f / 127.0f);
  }
}

// ---- quant both: blocks [0,4704) do x -> Aq, [4704,4776) do w -> Wq -------
// x thread g handles floats [8g, 8g+8) = patch row (b,c,h,gy):
//   g = ((b*3+c)*224 + h)*28 + gy ; float idx = 8g  (fully coalesced reads)
//   Aq octet idx = m*24 + c*8 + (h&7),  m = b*784 + (h>>3)*28 + gy
#define NQX 4704
#define NQW 72
__global__ void quant_xw_k(const float4* __restrict__ x,
                           const float4* __restrict__ w,
                           uint4* __restrict__ Aq, uint4* __restrict__ Wq,
                           const float* __restrict__ slots) {
  if (blockIdx.x < NQX) {
    int g = blockIdx.x * 256 + threadIdx.x;       // < 1,204,224
    float inv = 1.0f / slots[0];
    float4 a0 = x[g * 2], a1 = x[g * 2 + 1];
    int gy = g % 28;
    int t  = g / 28;
    int h  = t % 224;
    int u2 = t / 224;
    int c  = u2 % 3;
    int b  = u2 / 3;
    int m  = b * 784 + (h >> 3) * 28 + gy;
    Aq[m * 24 + c * 8 + (h & 7)] = quant8(a0, a1, inv);
  } else {
    int g = (blockIdx.x - NQX) * 256 + threadIdx.x;  // < 18,432
    float inv = 1.0f / slots[1];
    float4 a0 = w[g * 2], a1 = w[g * 2 + 1];
    Wq[g] = quant8(a0, a1, inv);                  // flat order == [d][k]
  }
}

// ---------------------------------------------------------------------------
// Pure code-GEMM. mfma_f32_16x16x32_bf16 verified layouts (m89/m120):
//   A frag: A[m = lane&15][k = (lane>>4)*8 + j]  -> Aq uint4 @ m*24 + k/8
//   B frag: W[n = lane&15][k = (lane>>4)*8 + j]  -> Wq uint4 @ n*24 + k/8
//   D:      row = (lane>>4)*4 + reg, col = lane&15
// ---------------------------------------------------------------------------
__global__ __launch_bounds__(256) void gemm_k(
    const uint4* __restrict__ Aq, const uint4* __restrict__ Wq,
    const float* __restrict__ bias, const float* __restrict__ slots,
    float* __restrict__ out) {
  const int tid  = threadIdx.x;
  const int lane = tid & 63;
  const int wid  = tid >> 6;
  const int wm   = wid >> 1;   // 0..1
  const int wn   = wid & 1;    // 0..1
  const int lm   = lane & 15;
  const int lq   = lane >> 4;  // 0..3
  const int m0   = blockIdx.x * 128;   // 392 m-tiles (392%8==0 -> XCD-local)
  const int n0   = blockIdx.y * 128;   // 6 n-tiles

  int abase[4], bbase[4];
#pragma unroll
  for (int tm = 0; tm < 4; ++tm)
    abase[tm] = (m0 + wm * 64 + tm * 16 + lm) * 24 + lq;
#pragma unroll
  for (int tn = 0; tn < 4; ++tn)
    bbase[tn] = (n0 + wn * 64 + tn * 16 + lm) * 24 + lq;

  f32x4 acc[4][4] = {};

#pragma unroll
  for (int ks = 0; ks < 6; ++ks) {     // k-octet index = ks*4 + lq
    bf16x8 af[4], bf[4];
#pragma unroll
    for (int tm = 0; tm < 4; ++tm)
      af[tm] = __builtin_bit_cast(bf16x8, Aq[abase[tm] + ks * 4]);
#pragma unroll
    for (int tn = 0; tn < 4; ++tn)
      bf[tn] = __builtin_bit_cast(bf16x8, Wq[bbase[tn] + ks * 4]);
#pragma unroll
    for (int tm = 0; tm < 4; ++tm)
#pragma unroll
      for (int tn = 0; tn < 4; ++tn)
        acc[tm][tn] = __builtin_amdgcn_mfma_f32_16x16x32_bf16(
            af[tm], bf[tn], acc[tm][tn], 0, 0, 0);
  }

  const float scale = slots[0] * slots[1];
#pragma unroll
  for (int tn = 0; tn < 4; ++tn) {
    int col = n0 + wn * 64 + tn * 16 + lm;
    float bv = bias[col];
#pragma unroll
    for (int tm = 0; tm < 4; ++tm) {
      int rbase = m0 + wm * 64 + tm * 16 + lq * 4;
#pragma unroll
      for (int r = 0; r < 4; ++r)
        out[(size_t)(rbase + r) * 768 + col] = acc[tm][tn][r] * scale + bv;
    }
  }
}

// ---------------------------------------------------------------------------

extern "C" void kernel_launch(void* const* d_in, const int* in_sizes, int n_in,
                              void* d_out, int out_size, void* d_ws, size_t ws_size,
                              hipStream_t stream) {
  const float4* x = (const float4*)d_in[0];      // 9,633,792 fp32
  const float4* w = (const float4*)d_in[1];      //   147,456 fp32
  const float* bias = (const float*)d_in[2];     //       768 fp32
  float* out = (float*)d_out;                    // 38,535,168 fp32

  char* ws = (char*)d_ws;
  float* slots    = (float*)ws;                  // [0]=s_x, [1]=s_w
  float* partials = (float*)(ws + 256);          // 1088 floats
  uint4* Wq       = (uint4*)(ws + 8192);         //   294,912 B of bf16 codes
  uint4* Aq       = (uint4*)(ws + 8192 + 294912);// 19,267,584 B of bf16 codes

  const int nx4 = 9633792 / 4;   // 2,408,448
  const int nw4 = 147456 / 4;    //    36,864

  absmax_k<<<NBX + NBW, 256, 0, stream>>>(x, nx4, w, nw4, partials);
  finalize_k<<<1, 1024, 0, stream>>>(partials, slots);
  quant_xw_k<<<NQX + NQW, 256, 0, stream>>>(x, w, Aq, Wq, slots);
  gemm_k<<<dim3(392, 6), 256, 0, stream>>>(Aq, Wq, bias, slots, out);
}